// Round 1
// baseline (112.111 us; speedup 1.0000x reference)
//
#include <hip/hip_runtime.h>

// Separable 3D Gaussian blur (sigma=1, truncate=3 -> 7 taps), SAME zero padding.
// Input/output: (N=2, D=160, H=160, W=160, C=4) float32, treated as float4 over C.
// Fused single pass: per block, 16x16 (H,W) tile streamed along D with a
// 7-slice register ring; W-blur and H-blur done in LDS per slice.

#define TILE 16
#define CHUNK 32           // output D-slices per block
#define DIM 160

// Gaussian weights: exp(-0.5*x^2), x=-3..3, normalized (computed in double, cast).
#define W0 0.004433048f
#define W1 0.054005582f
#define W2 0.242036229f
#define W3 0.399050300f

__device__ __forceinline__ float4 blur7(float4 a0, float4 a1, float4 a2, float4 a3,
                                        float4 a4, float4 a5, float4 a6) {
    float4 r;
    r.x = W0 * (a0.x + a6.x) + W1 * (a1.x + a5.x) + W2 * (a2.x + a4.x) + W3 * a3.x;
    r.y = W0 * (a0.y + a6.y) + W1 * (a1.y + a5.y) + W2 * (a2.y + a4.y) + W3 * a3.y;
    r.z = W0 * (a0.z + a6.z) + W1 * (a1.z + a5.z) + W2 * (a2.z + a4.z) + W3 * a3.z;
    r.w = W0 * (a0.w + a6.w) + W1 * (a1.w + a5.w) + W2 * (a2.w + a4.w) + W3 * a3.w;
    return r;
}

__global__ __launch_bounds__(256, 8)
void gauss3d_fused(const float4* __restrict__ in, float4* __restrict__ out) {
    // decode block: (tw, th, chunk, n)
    int bid = blockIdx.x;
    int tw    = bid % (DIM / TILE);  bid /= (DIM / TILE);
    int th    = bid % (DIM / TILE);  bid /= (DIM / TILE);
    int chunk = bid % (DIM / CHUNK); bid /= (DIM / CHUNK);
    int n     = bid;

    const int h0 = th * TILE;
    const int w0 = tw * TILE;
    const int d0 = chunk * CHUNK;

    // LDS: raw halo tile (22x22 float4, rows padded to 23) and W-blurred (22x16, pad 17)
    __shared__ float4 raw[22][23];
    __shared__ float4 wb[22][17];

    const int tid = threadIdx.x;
    const int lh = tid >> 4;     // 0..15
    const int lw = tid & 15;     // 0..15

    const size_t nbase = (size_t)n * DIM * DIM * DIM;

    float4 z = make_float4(0.f, 0.f, 0.f, 0.f);
    float4 r0 = z, r1 = z, r2 = z, r3 = z, r4 = z, r5 = z, r6 = z;

    for (int din = d0 - 3; din <= d0 + CHUNK + 2; ++din) {
        float4 v = z;
        if (din >= 0 && din < DIM) {           // uniform branch across block
            const float4* src = in + nbase + (size_t)din * DIM * DIM;
            // 1) stage 22x22 halo tile (zero-pad outside image)
            #pragma unroll
            for (int i = tid; i < 22 * 22; i += 256) {
                int rr = i / 22, cc = i % 22;
                int gh = h0 + rr - 3, gw = w0 + cc - 3;
                float4 val = z;
                if (gh >= 0 && gh < DIM && gw >= 0 && gw < DIM)
                    val = src[gh * DIM + gw];
                raw[rr][cc] = val;
            }
            __syncthreads();
            // 2) W-blur: 22 rows x 16 cols
            #pragma unroll
            for (int i = tid; i < 22 * 16; i += 256) {
                int rr = i / 16, cc = i % 16;
                wb[rr][cc] = blur7(raw[rr][cc], raw[rr][cc + 1], raw[rr][cc + 2],
                                   raw[rr][cc + 3], raw[rr][cc + 4], raw[rr][cc + 5],
                                   raw[rr][cc + 6]);
            }
            __syncthreads();
            // 3) H-blur at this thread's (lh, lw)
            v = blur7(wb[lh][lw], wb[lh + 1][lw], wb[lh + 2][lw], wb[lh + 3][lw],
                      wb[lh + 4][lw], wb[lh + 5][lw], wb[lh + 6][lw]);
            __syncthreads();   // protect LDS before next slice overwrites
        }
        // 4) register ring shift (static indices -> stays in VGPRs)
        r0 = r1; r1 = r2; r2 = r3; r3 = r4; r4 = r5; r5 = r6; r6 = v;

        const int dout = din - 3;
        if (dout >= d0 && dout < d0 + CHUNK) {
            float4 o = blur7(r0, r1, r2, r3, r4, r5, r6);
            out[nbase + ((size_t)dout * DIM + (h0 + lh)) * DIM + (w0 + lw)] = o;
        }
    }
}

extern "C" void kernel_launch(void* const* d_in, const int* in_sizes, int n_in,
                              void* d_out, int out_size, void* d_ws, size_t ws_size,
                              hipStream_t stream) {
    const float4* in = (const float4*)d_in[0];
    float4* out = (float4*)d_out;
    const int nblocks = 2 * (DIM / TILE) * (DIM / TILE) * (DIM / CHUNK); // 1000
    gauss3d_fused<<<nblocks, 256, 0, stream>>>(in, out);
}